// Round 7
// baseline (164.855 us; speedup 1.0000x reference)
//
#include <hip/hip_runtime.h>

// ---------------------------------------------------------------------------
// Fully-fused KAN-conv MLP: one block = one image through all layers.
// Cardinal cubic B-spline: basis_j(x) = B3(u - j), u = 2.5x+5.5 (4 taps).
// phi is SoA in LDS: bas[pix] = uint4 (8 bf16 basis taps, 1x ds_read_b128,
// 16B/lane stride = conflict-free) + ext[pix] = silu (b32). Featurize builds
// the 8-slot window in registers (64->128-bit funnel shift by 16*(t-3)) ->
// 2 DS writes/pixel. Conv = dense contraction, merged weights
// V[c][ky][kx][j9][o] (j8 = base weight, wave-uniform -> s_loads).
// fc1 weights transposed+bf16-packed W1t[k(164)][u(256)] (outs 2u,2u+1).
// ---------------------------------------------------------------------------

__device__ __forceinline__ unsigned short f2bf(float x) {
  unsigned int b = __float_as_uint(x);
  b = b + 0x7fffu + ((b >> 16) & 1u);          // RNE
  return (unsigned short)(b >> 16);
}
__device__ __forceinline__ float bflo(unsigned int u) { return __uint_as_float(u << 16); }
__device__ __forceinline__ float bfhi(unsigned int u) { return __uint_as_float(u & 0xffff0000u); }

// Compute basis window (8 bf16 packed in uint4) + silu, all in registers.
__device__ __forceinline__ void featurize_regs(float v, uint4& bs, float& silu) {
  silu = v / (1.0f + __expf(-v));
  bs.x = 0u; bs.y = 0u; bs.z = 0u; bs.w = 0u;
  float u = fmaf(v, 2.5f, 5.5f);
  if (u >= 0.0f && u < 11.0f) {
    float tf = floorf(u);
    float f = u - tf, f2 = f * f, f3 = f2 * f, om = 1.0f - f;
    const float c6 = 1.0f / 6.0f;
    float w0 = om * om * om * c6;
    float w1 = (3.0f * f3 - 6.0f * f2 + 4.0f) * c6;
    float w2 = (-3.0f * f3 + 3.0f * f2 + 3.0f * f + 1.0f) * c6;
    float w3 = f3 * c6;
    unsigned long long w01 =
        (unsigned long long)f2bf(w0) |
        ((unsigned long long)f2bf(w1) << 16) |
        ((unsigned long long)f2bf(w2) << 32) |
        ((unsigned long long)f2bf(w3) << 48);
    int t = (int)tf;                 // 0..10; window starts at slot t-3
    int s = 16 * t - 48;             // bit shift into 128-bit field
    unsigned long long lo, hi;
    if (s >= 0) {
      lo = (s < 64) ? (w01 << s) : 0ull;
      hi = (s == 0) ? 0ull : ((s < 64) ? (w01 >> (64 - s)) : (w01 << (s - 64)));
    } else {
      lo = w01 >> (-s);
      hi = 0ull;
    }
    bs.x = (unsigned int)lo; bs.y = (unsigned int)(lo >> 32);
    bs.z = (unsigned int)hi; bs.w = (unsigned int)(hi >> 32);
  }
}

// Read one record (8 basis + silu) : 1 b128 + 1 b32.
__device__ __forceinline__ void read9(const uint4* __restrict__ bas,
                                      const float* __restrict__ ext,
                                      int r, float* __restrict__ ph) {
  uint4 q = bas[r];
  ph[0] = bflo(q.x); ph[1] = bfhi(q.x);
  ph[2] = bflo(q.y); ph[3] = bfhi(q.y);
  ph[4] = bflo(q.z); ph[5] = bfhi(q.z);
  ph[6] = bflo(q.w); ph[7] = bfhi(q.w);
  ph[8] = ext[r];
}

// ---------------- prep: V1/V2/V3 merged conv weights + W1t bf16 -------------
__global__ __launch_bounds__(256) void k_prep(
    const float* __restrict__ bw1, const float* __restrict__ sw1,
    const float* __restrict__ bw2, const float* __restrict__ sw2,
    const float* __restrict__ bw3, const float* __restrict__ sw3,
    const float* __restrict__ w1,
    float* __restrict__ V1, float* __restrict__ V2, float* __restrict__ V3,
    unsigned int* __restrict__ W1t) {
  int t = blockIdx.x * 256 + threadIdx.x;
  if (t < 405) {  // L1: CIN=1, COUT=5  idx=((ky*3+kx)*9+j)*5+o
    int o = t % 5, j = (t / 5) % 9, kx = (t / 45) % 3, ky = t / 135;
    int in = ky * 3 + kx;
    V1[t] = (j < 8) ? sw1[(o * 9 + in) * 8 + j] : bw1[o * 9 + in];
  }
  if (t < 2025) { // L2: CIN=5, COUT=5  idx=(((c*3+ky)*3+kx)*9+j)*5+o
    int o = t % 5, j = (t / 5) % 9, kx = (t / 45) % 3, ky = (t / 135) % 3, c = t / 405;
    int in = c * 9 + ky * 3 + kx;
    V2[t] = (j < 8) ? sw2[(o * 45 + in) * 8 + j] : bw2[o * 45 + in];
  }
  if (t < 810) {  // L3: CIN=5, COUT=2  idx=(((c*3+ky)*3+kx)*9+j)*2+o
    int o = t % 2, j = (t / 2) % 9, kx = (t / 18) % 3, ky = (t / 54) % 3, c = t / 162;
    int in = c * 9 + ky * 3 + kx;
    V3[t] = (j < 8) ? sw3[(o * 45 + in) * 8 + j] : bw3[o * 45 + in];
  }
  if (t < 164 * 256) { // W1t[k][u] packs outputs (2u, 2u+1); k padded to 164
    int k = t / 256, u = t % 256;
    int o0 = 2 * u, o1 = 2 * u + 1;
    unsigned int lo = (k < 162 && o0 < 500) ? f2bf(w1[o0 * 162 + k]) : 0;
    unsigned int hi = (k < 162 && o1 < 500) ? f2bf(w1[o1 * 162 + k]) : 0;
    W1t[t] = lo | (hi << 16);
  }
}

// ---------------- the fused per-image kernel --------------------------------
__global__ __launch_bounds__(256) void k_fused(
    const float* __restrict__ x,
    const float* __restrict__ V1, const float* __restrict__ V2,
    const float* __restrict__ V3,
    const unsigned int* __restrict__ W1t,
    const float* __restrict__ b1,
    const float* __restrict__ W2, const float* __restrict__ b2,
    float* __restrict__ out) {
  __shared__ uint4 bas[845];              // 13,520 B
  __shared__ float ext[845];              //  3,380 B
  __shared__ float hbuf[845];             //  3,380 B (h1/h2/h3/fc1out/partials)
  const int b = blockIdx.x;
  const int tid = threadIdx.x;

  // P1: featurize input image (784 px)
  for (int l = tid; l < 784; l += 256) {
    uint4 bs; float sl;
    featurize_regs(x[b * 784 + l], bs, sl);
    bas[l] = bs; ext[l] = sl;
  }
  __syncthreads();

  // P2: conv1 (1->5) + 2x2 maxpool -> h1 = hbuf[o*169 + p]
  if (tid < 169) {
    int py = tid / 13, px = tid % 13;
    int r0 = py * 2, c0 = px * 2;
    float wacc[4][5];
    #pragma unroll
    for (int wi = 0; wi < 4; ++wi)
      #pragma unroll
      for (int o = 0; o < 5; ++o) wacc[wi][o] = 0.0f;
    #pragma unroll
    for (int r = 0; r < 4; ++r) {
      #pragma unroll
      for (int c = 0; c < 4; ++c) {
        float ph[9];
        read9(bas, ext, (r0 + r) * 28 + c0 + c, ph);
        #pragma unroll
        for (int dy = 0; dy < 2; ++dy) {
          #pragma unroll
          for (int dx = 0; dx < 2; ++dx) {
            int ky = r - dy, kx = c - dx;
            if (ky >= 0 && ky < 3 && kx >= 0 && kx < 3) {
              const float* wp = V1 + (ky * 3 + kx) * 45;
              #pragma unroll
              for (int j = 0; j < 9; ++j)
                #pragma unroll
                for (int o = 0; o < 5; ++o)
                  wacc[dy * 2 + dx][o] = fmaf(ph[j], wp[j * 5 + o], wacc[dy * 2 + dx][o]);
            }
          }
        }
      }
    }
    #pragma unroll
    for (int o = 0; o < 5; ++o) {
      float m = fmaxf(fmaxf(wacc[0][o], wacc[1][o]), fmaxf(wacc[2][o], wacc[3][o]));
      hbuf[o * 169 + tid] = m;
    }
  }
  __syncthreads();

  // P3: featurize h1 (845 px)
  for (int l = tid; l < 845; l += 256) {
    uint4 bs; float sl;
    featurize_regs(hbuf[l], bs, sl);
    bas[l] = bs; ext[l] = sl;
  }
  __syncthreads();

  // P4: conv2 (5->5) -> h2 = hbuf[o*121 + pos]
  if (tid < 121) {
    int y = tid / 11, xx = tid % 11;
    float acc[5] = {0.f, 0.f, 0.f, 0.f, 0.f};
    #pragma unroll 1
    for (int cky = 0; cky < 15; ++cky) {
      int c = cky / 3, ky = cky % 3;
      const float* wp = V2 + cky * 135;      // [kx][j9][o5]
      int base = c * 169 + (y + ky) * 13 + xx;
      #pragma unroll
      for (int kx = 0; kx < 3; ++kx) {
        float ph[9];
        read9(bas, ext, base + kx, ph);
        #pragma unroll
        for (int j = 0; j < 9; ++j)
          #pragma unroll
          for (int o = 0; o < 5; ++o)
            acc[o] = fmaf(ph[j], wp[(kx * 9 + j) * 5 + o], acc[o]);
      }
    }
    #pragma unroll
    for (int o = 0; o < 5; ++o) hbuf[o * 121 + tid] = acc[o];
  }
  __syncthreads();

  // P5: featurize h2 (605 px)
  for (int l = tid; l < 605; l += 256) {
    uint4 bs; float sl;
    featurize_regs(hbuf[l], bs, sl);
    bas[l] = bs; ext[l] = sl;
  }
  __syncthreads();

  // P6: conv3 (5->2) -> h3 = hbuf[0..161]; pad hbuf[162..163]=0
  if (tid < 81) {
    int y = tid / 9, xx = tid % 9;
    float acc[2] = {0.f, 0.f};
    #pragma unroll 1
    for (int cky = 0; cky < 15; ++cky) {
      int c = cky / 3, ky = cky % 3;
      const float* wp = V3 + cky * 54;       // [kx][j9][o2]
      int base = c * 121 + (y + ky) * 11 + xx;
      #pragma unroll
      for (int kx = 0; kx < 3; ++kx) {
        float ph[9];
        read9(bas, ext, base + kx, ph);
        #pragma unroll
        for (int j = 0; j < 9; ++j)
          #pragma unroll
          for (int o = 0; o < 2; ++o)
            acc[o] = fmaf(ph[j], wp[kx * 18 + j * 2 + o], acc[o]);
      }
    }
    hbuf[tid] = acc[0];
    hbuf[81 + tid] = acc[1];
  }
  if (tid == 81) { hbuf[162] = 0.0f; hbuf[163] = 0.0f; }
  __syncthreads();

  // P7: fc1 (162->500) + bias + ReLU -> hbuf[200 + o]
  if (tid < 250) {
    float a0 = 0.0f, a1 = 0.0f;
    #pragma unroll 1
    for (int k4 = 0; k4 < 41; ++k4) {
      float4 h = *(const float4*)&hbuf[k4 * 4];
      unsigned int w0 = W1t[(k4 * 4 + 0) * 256 + tid];
      unsigned int w1v = W1t[(k4 * 4 + 1) * 256 + tid];
      unsigned int w2v = W1t[(k4 * 4 + 2) * 256 + tid];
      unsigned int w3v = W1t[(k4 * 4 + 3) * 256 + tid];
      a0 = fmaf(bflo(w0), h.x, a0);  a1 = fmaf(bfhi(w0), h.x, a1);
      a0 = fmaf(bflo(w1v), h.y, a0); a1 = fmaf(bfhi(w1v), h.y, a1);
      a0 = fmaf(bflo(w2v), h.z, a0); a1 = fmaf(bfhi(w2v), h.z, a1);
      a0 = fmaf(bflo(w3v), h.w, a0); a1 = fmaf(bfhi(w3v), h.w, a1);
    }
    int o0 = 2 * tid, o1 = 2 * tid + 1;
    float v0 = a0 + b1[o0], v1 = a1 + b1[o1];
    hbuf[200 + o0] = v0 > 0.0f ? v0 : 0.0f;
    hbuf[200 + o1] = v1 > 0.0f ? v1 : 0.0f;
  }
  __syncthreads();

  // P8: fc2 partials: (o,part) -> hbuf[o*16+part]; k = part*4 + j*64
  // (16 B/lane stride -> conflict-free b128 reads)
  if (tid < 160) {
    int o = tid >> 4, part = tid & 15;
    float s = 0.0f;
    #pragma unroll
    for (int j = 0; j < 8; ++j) {
      int k = part * 4 + j * 64;
      if (k <= 496) {
        float4 w = *(const float4*)&W2[o * 500 + k];
        float4 h = *(const float4*)&hbuf[200 + k];
        s += w.x * h.x + w.y * h.y + w.z * h.z + w.w * h.w;
      }
    }
    hbuf[tid] = s;
  }
  __syncthreads();

  // P9: reduce 16 partials per output, add bias, store
  if (tid < 10) {
    float s = 0.0f;
    #pragma unroll
    for (int p = 0; p < 16; ++p) s += hbuf[tid * 16 + p];
    out[b * 10 + tid] = s + b2[tid];
  }
}

// ---------------------------------------------------------------------------
extern "C" void kernel_launch(void* const* d_in, const int* in_sizes, int n_in,
                              void* d_out, int out_size, void* d_ws, size_t ws_size,
                              hipStream_t stream) {
  (void)in_sizes; (void)n_in; (void)out_size; (void)ws_size;
  const float* x   = (const float*)d_in[0];
  const float* bw1 = (const float*)d_in[1];
  const float* sw1 = (const float*)d_in[2];
  const float* bw2 = (const float*)d_in[3];
  const float* sw2 = (const float*)d_in[4];
  const float* bw3 = (const float*)d_in[5];
  const float* sw3 = (const float*)d_in[6];
  const float* w1  = (const float*)d_in[7];
  const float* b1  = (const float*)d_in[8];
  const float* w2  = (const float*)d_in[9];
  const float* b2  = (const float*)d_in[10];
  float* out = (float*)d_out;

  char* ws = (char*)d_ws;
  float*        V1  = (float*)(ws);               // 405 f  (1,620 B)
  float*        V2  = (float*)(ws + 2048);        // 2025 f (8,100 B)
  float*        V3  = (float*)(ws + 10752);       // 810 f  (3,240 B)
  unsigned int* W1t = (unsigned int*)(ws + 14336);// 164*256 uints (167,936 B)

  k_prep<<<164, 256, 0, stream>>>(bw1, sw1, bw2, sw2, bw3, sw3, w1,
                                  V1, V2, V3, W1t);
  k_fused<<<2048, 256, 0, stream>>>(x, V1, V2, V3, W1t, b1, w2, b2, out);
}

// Round 8
// 141.036 us; speedup vs baseline: 1.1689x; 1.1689x over previous
//
#include <hip/hip_runtime.h>

// ---------------------------------------------------------------------------
// Fully-fused KAN-conv MLP: one block = one image through all layers.
// Cardinal cubic B-spline: basis_j(x) = B3(u - j), u = 2.5x+5.5 (4 taps).
// phi is SoA in LDS as F16: bas[pix] = uint4 (8 f16 basis taps, 1 ds_read_b128)
// + ext[pix] = silu fp32. Conv contraction uses v_dot2_f32_f16
// (__builtin_amdgcn_fdot2): packed f16 pairs go straight into dot2 -> no
// unpack VALU, half the FMA issues. Weights pre-paired f16 (j,j+1) per out
// by k_prep (wave-uniform -> s_loads); base/silu weight stays fp32 fmaf.
// fc1: h3 repacked to f16 pairs; 81 dot2 + coalesced uint2 weight loads.
// ---------------------------------------------------------------------------

typedef _Float16 h2 __attribute__((ext_vector_type(2)));

__device__ __forceinline__ h2 u2h(unsigned int u) {
  union { unsigned int x; h2 h; } v; v.x = u; return v.h;
}
__device__ __forceinline__ unsigned short f2h_bits(float x) {
  union { _Float16 h; unsigned short u; } v; v.h = (_Float16)x; return v.u;
}
__device__ __forceinline__ unsigned int pack2h(float a, float b) {
  return (unsigned int)f2h_bits(a) | ((unsigned int)f2h_bits(b) << 16);
}
__device__ __forceinline__ float fdot2(h2 a, h2 b, float c) {
  return __builtin_amdgcn_fdot2(a, b, c, false);
}

// Basis window (8 f16 packed in uint4) + silu, all in registers.
__device__ __forceinline__ void featurize_regs(float v, uint4& bs, float& silu) {
  silu = v / (1.0f + __expf(-v));
  bs.x = 0u; bs.y = 0u; bs.z = 0u; bs.w = 0u;
  float u = fmaf(v, 2.5f, 5.5f);
  if (u >= 0.0f && u < 11.0f) {
    float tf = floorf(u);
    float f = u - tf, f2 = f * f, f3 = f2 * f, om = 1.0f - f;
    const float c6 = 1.0f / 6.0f;
    float w0 = om * om * om * c6;
    float w1 = (3.0f * f3 - 6.0f * f2 + 4.0f) * c6;
    float w2 = (-3.0f * f3 + 3.0f * f2 + 3.0f * f + 1.0f) * c6;
    float w3 = f3 * c6;
    unsigned long long w01 =
        (unsigned long long)f2h_bits(w0) |
        ((unsigned long long)f2h_bits(w1) << 16) |
        ((unsigned long long)f2h_bits(w2) << 32) |
        ((unsigned long long)f2h_bits(w3) << 48);
    int t = (int)tf;                 // 0..10; window starts at slot t-3
    int s = 16 * t - 48;             // bit shift into 128-bit field
    unsigned long long lo, hi;
    if (s >= 0) {
      lo = (s < 64) ? (w01 << s) : 0ull;
      hi = (s == 0) ? 0ull : ((s < 64) ? (w01 >> (64 - s)) : (w01 << (s - 64)));
    } else {
      lo = w01 >> (-s);
      hi = 0ull;
    }
    bs.x = (unsigned int)lo; bs.y = (unsigned int)(lo >> 32);
    bs.z = (unsigned int)hi; bs.w = (unsigned int)(hi >> 32);
  }
}

// ---------------- prep: f16-paired conv weights + W1p ------------------------
// V*s layout: [tap(in)][o][pair(4)] uints, pair p = (j=2p, 2p+1).
// V*b layout: [tap(in)][o] float (base weight).
// W1p layout: [kp(81)][o(512 pad)] uint = pack(w1[o][2kp], w1[o][2kp+1]).
__global__ __launch_bounds__(256) void k_prep(
    const float* __restrict__ bw1, const float* __restrict__ sw1,
    const float* __restrict__ bw2, const float* __restrict__ sw2,
    const float* __restrict__ bw3, const float* __restrict__ sw3,
    const float* __restrict__ w1,
    unsigned int* __restrict__ V1s, float* __restrict__ V1b,
    unsigned int* __restrict__ V2s, float* __restrict__ V2b,
    unsigned int* __restrict__ V3s, float* __restrict__ V3b,
    unsigned int* __restrict__ W1p) {
  int t = blockIdx.x * 256 + threadIdx.x;
  if (t < 180) {  // L1: 9 taps x 5 outs x 4 pairs
    int p = t & 3, o = (t >> 2) % 5, in = t / 20;
    V1s[t] = pack2h(sw1[(o * 9 + in) * 8 + 2 * p], sw1[(o * 9 + in) * 8 + 2 * p + 1]);
  }
  if (t < 45)  { int o = t % 5, in = t / 5; V1b[t] = bw1[o * 9 + in]; }
  if (t < 900) { // L2: 45 taps x 5 outs x 4 pairs
    int p = t & 3, o = (t >> 2) % 5, in = t / 20;
    V2s[t] = pack2h(sw2[(o * 45 + in) * 8 + 2 * p], sw2[(o * 45 + in) * 8 + 2 * p + 1]);
  }
  if (t < 225) { int o = t % 5, in = t / 5; V2b[t] = bw2[o * 45 + in]; }
  if (t < 360) { // L3: 45 taps x 2 outs x 4 pairs
    int p = t & 3, o = (t >> 2) & 1, in = t / 8;
    V3s[t] = pack2h(sw3[(o * 45 + in) * 8 + 2 * p], sw3[(o * 45 + in) * 8 + 2 * p + 1]);
  }
  if (t < 90)  { int o = t % 2, in = t / 2; V3b[t] = bw3[o * 45 + in]; }
  if (t < 81 * 512) {
    int kp = t >> 9, o = t & 511;
    W1p[t] = (o < 500) ? pack2h(w1[o * 162 + 2 * kp], w1[o * 162 + 2 * kp + 1]) : 0u;
  }
}

// ---------------- the fused per-image kernel --------------------------------
__global__ __launch_bounds__(256) void k_fused(
    const float* __restrict__ x,
    const unsigned int* __restrict__ V1s, const float* __restrict__ V1b,
    const unsigned int* __restrict__ V2s, const float* __restrict__ V2b,
    const unsigned int* __restrict__ V3s, const float* __restrict__ V3b,
    const unsigned int* __restrict__ W1p,
    const float* __restrict__ b1,
    const float* __restrict__ W2, const float* __restrict__ b2,
    float* __restrict__ out) {
  __shared__ uint4 bas[845];              // 13,520 B
  __shared__ float ext[845];              //  3,380 B
  __shared__ float hbuf[845];             //  3,380 B (h1/h2/h3/fc1out/partials)
  __shared__ unsigned int hpk[81];        //    324 B (h3 as f16 pairs)
  const int b = blockIdx.x;
  const int tid = threadIdx.x;

  // P1: featurize input image (784 px)
  for (int l = tid; l < 784; l += 256) {
    uint4 bs; float sl;
    featurize_regs(x[b * 784 + l], bs, sl);
    bas[l] = bs; ext[l] = sl;
  }
  __syncthreads();

  // P2: conv1 (1->5) + 2x2 maxpool -> h1 = hbuf[o*169 + p]
  if (tid < 169) {
    int py = tid / 13, px = tid % 13;
    int r0 = py * 2, c0 = px * 2;
    float wacc[4][5];
    #pragma unroll
    for (int wi = 0; wi < 4; ++wi)
      #pragma unroll
      for (int o = 0; o < 5; ++o) wacc[wi][o] = 0.0f;
    #pragma unroll
    for (int r = 0; r < 4; ++r) {
      #pragma unroll
      for (int c = 0; c < 4; ++c) {
        uint4 q = bas[(r0 + r) * 28 + c0 + c];
        float sl = ext[(r0 + r) * 28 + c0 + c];
        h2 a0 = u2h(q.x), a1 = u2h(q.y), a2 = u2h(q.z), a3 = u2h(q.w);
        #pragma unroll
        for (int dy = 0; dy < 2; ++dy) {
          #pragma unroll
          for (int dx = 0; dx < 2; ++dx) {
            int ky = r - dy, kx = c - dx;
            if (ky >= 0 && ky < 3 && kx >= 0 && kx < 3) {
              const unsigned int* wp = V1s + (ky * 3 + kx) * 20;
              const float* bp = V1b + (ky * 3 + kx) * 5;
              #pragma unroll
              for (int o = 0; o < 5; ++o) {
                float acc = wacc[dy * 2 + dx][o];
                acc = fdot2(a0, u2h(wp[o * 4 + 0]), acc);
                acc = fdot2(a1, u2h(wp[o * 4 + 1]), acc);
                acc = fdot2(a2, u2h(wp[o * 4 + 2]), acc);
                acc = fdot2(a3, u2h(wp[o * 4 + 3]), acc);
                wacc[dy * 2 + dx][o] = fmaf(sl, bp[o], acc);
              }
            }
          }
        }
      }
    }
    #pragma unroll
    for (int o = 0; o < 5; ++o) {
      float m = fmaxf(fmaxf(wacc[0][o], wacc[1][o]), fmaxf(wacc[2][o], wacc[3][o]));
      hbuf[o * 169 + tid] = m;
    }
  }
  __syncthreads();

  // P3: featurize h1 (845 px)
  for (int l = tid; l < 845; l += 256) {
    uint4 bs; float sl;
    featurize_regs(hbuf[l], bs, sl);
    bas[l] = bs; ext[l] = sl;
  }
  __syncthreads();

  // P4: conv2 (5->5) -> h2 = hbuf[o*121 + pos]
  if (tid < 121) {
    int y = tid / 11, xx = tid % 11;
    float acc[5] = {0.f, 0.f, 0.f, 0.f, 0.f};
    #pragma unroll 1
    for (int cky = 0; cky < 15; ++cky) {
      int c = cky / 3, ky = cky % 3;
      int base = c * 169 + (y + ky) * 13 + xx;
      #pragma unroll
      for (int kx = 0; kx < 3; ++kx) {
        uint4 q = bas[base + kx];
        float sl = ext[base + kx];
        h2 a0 = u2h(q.x), a1 = u2h(q.y), a2 = u2h(q.z), a3 = u2h(q.w);
        const unsigned int* wp = V2s + (cky * 3 + kx) * 20;
        const float* bp = V2b + (cky * 3 + kx) * 5;
        #pragma unroll
        for (int o = 0; o < 5; ++o) {
          float a = acc[o];
          a = fdot2(a0, u2h(wp[o * 4 + 0]), a);
          a = fdot2(a1, u2h(wp[o * 4 + 1]), a);
          a = fdot2(a2, u2h(wp[o * 4 + 2]), a);
          a = fdot2(a3, u2h(wp[o * 4 + 3]), a);
          acc[o] = fmaf(sl, bp[o], a);
        }
      }
    }
    #pragma unroll
    for (int o = 0; o < 5; ++o) hbuf[o * 121 + tid] = acc[o];
  }
  __syncthreads();

  // P5: featurize h2 (605 px)
  for (int l = tid; l < 605; l += 256) {
    uint4 bs; float sl;
    featurize_regs(hbuf[l], bs, sl);
    bas[l] = bs; ext[l] = sl;
  }
  __syncthreads();

  // P6: conv3 (5->2) -> h3 = hbuf[0..161]
  if (tid < 81) {
    int y = tid / 9, xx = tid % 9;
    float acc[2] = {0.f, 0.f};
    #pragma unroll 1
    for (int cky = 0; cky < 15; ++cky) {
      int c = cky / 3, ky = cky % 3;
      int base = c * 121 + (y + ky) * 11 + xx;
      #pragma unroll
      for (int kx = 0; kx < 3; ++kx) {
        uint4 q = bas[base + kx];
        float sl = ext[base + kx];
        h2 a0 = u2h(q.x), a1 = u2h(q.y), a2 = u2h(q.z), a3 = u2h(q.w);
        const unsigned int* wp = V3s + (cky * 3 + kx) * 8;
        const float* bp = V3b + (cky * 3 + kx) * 2;
        #pragma unroll
        for (int o = 0; o < 2; ++o) {
          float a = acc[o];
          a = fdot2(a0, u2h(wp[o * 4 + 0]), a);
          a = fdot2(a1, u2h(wp[o * 4 + 1]), a);
          a = fdot2(a2, u2h(wp[o * 4 + 2]), a);
          a = fdot2(a3, u2h(wp[o * 4 + 3]), a);
          acc[o] = fmaf(sl, bp[o], a);
        }
      }
    }
    hbuf[tid] = acc[0];
    hbuf[81 + tid] = acc[1];
  }
  __syncthreads();

  // P6b: repack h3 into f16 pairs hpk[81]
  if (tid < 81) hpk[tid] = pack2h(hbuf[2 * tid], hbuf[2 * tid + 1]);
  __syncthreads();

  // P7: fc1 (162->500) + bias + ReLU -> hbuf[200 + o]
  if (tid < 250) {
    float a0 = 0.0f, a1 = 0.0f;
    #pragma unroll 4
    for (int kp = 0; kp < 81; ++kp) {
      h2 hk = u2h(hpk[kp]);
      uint2 wv = *(const uint2*)(W1p + kp * 512 + 2 * tid);
      a0 = fdot2(hk, u2h(wv.x), a0);
      a1 = fdot2(hk, u2h(wv.y), a1);
    }
    int o0 = 2 * tid, o1 = 2 * tid + 1;
    float v0 = a0 + b1[o0], v1 = a1 + b1[o1];
    hbuf[200 + o0] = v0 > 0.0f ? v0 : 0.0f;
    hbuf[200 + o1] = v1 > 0.0f ? v1 : 0.0f;
  }
  __syncthreads();

  // P8: fc2 partials: (o,part) -> hbuf[o*16+part]; k = part*4 + j*64
  if (tid < 160) {
    int o = tid >> 4, part = tid & 15;
    float s = 0.0f;
    #pragma unroll
    for (int j = 0; j < 8; ++j) {
      int k = part * 4 + j * 64;
      if (k <= 496) {
        float4 w = *(const float4*)&W2[o * 500 + k];
        float4 h = *(const float4*)&hbuf[200 + k];
        s += w.x * h.x + w.y * h.y + w.z * h.z + w.w * h.w;
      }
    }
    hbuf[tid] = s;
  }
  __syncthreads();

  // P9: reduce 16 partials per output, add bias, store
  if (tid < 10) {
    float s = 0.0f;
    #pragma unroll
    for (int p = 0; p < 16; ++p) s += hbuf[tid * 16 + p];
    out[b * 10 + tid] = s + b2[tid];
  }
}

// ---------------------------------------------------------------------------
extern "C" void kernel_launch(void* const* d_in, const int* in_sizes, int n_in,
                              void* d_out, int out_size, void* d_ws, size_t ws_size,
                              hipStream_t stream) {
  (void)in_sizes; (void)n_in; (void)out_size; (void)ws_size;
  const float* x   = (const float*)d_in[0];
  const float* bw1 = (const float*)d_in[1];
  const float* sw1 = (const float*)d_in[2];
  const float* bw2 = (const float*)d_in[3];
  const float* sw2 = (const float*)d_in[4];
  const float* bw3 = (const float*)d_in[5];
  const float* sw3 = (const float*)d_in[6];
  const float* w1  = (const float*)d_in[7];
  const float* b1  = (const float*)d_in[8];
  const float* w2  = (const float*)d_in[9];
  const float* b2  = (const float*)d_in[10];
  float* out = (float*)d_out;

  char* ws = (char*)d_ws;
  unsigned int* V1s = (unsigned int*)(ws);          // 180 u  (720 B)
  float*        V1b = (float*)(ws + 768);           // 45 f   (180 B)
  unsigned int* V2s = (unsigned int*)(ws + 1024);   // 900 u  (3,600 B)
  float*        V2b = (float*)(ws + 4672);          // 225 f  (900 B)
  unsigned int* V3s = (unsigned int*)(ws + 5632);   // 360 u  (1,440 B)
  float*        V3b = (float*)(ws + 7168);          // 90 f   (360 B)
  unsigned int* W1p = (unsigned int*)(ws + 7680);   // 81*512 u (165,888 B)

  k_prep<<<162, 256, 0, stream>>>(bw1, sw1, bw2, sw2, bw3, sw3, w1,
                                  V1s, V1b, V2s, V2b, V3s, V3b, W1p);
  k_fused<<<2048, 256, 0, stream>>>(x, V1s, V1b, V2s, V2b, V3s, V3b, W1p,
                                    b1, w2, b2, out);
}